// Round 4
// baseline (93.240 us; speedup 1.0000x reference)
//
#include <hip/hip_runtime.h>
#include <math.h>

#define HW   224
#define NPIX (HW * HW)   // 50176
#define NB   64          // batch
#define NBPB 8           // reduction partial-blocks per batch image

// native vector type (ext_vector_type) — accepted by __builtin_nontemporal_store,
// same 16-byte layout/alignment as float4
typedef float fx4 __attribute__((ext_vector_type(4)));

// ---------------------------------------------------------------------------
// Kernel 1: per-image partial min/max of d = depth * object.
// 8 partials per image -> 512 blocks (2 blocks/CU on 256 CUs), no atomics.
// min/max are rounding-free, so any reduction order is bit-exact vs XLA.
// ---------------------------------------------------------------------------
__global__ __launch_bounds__(256) void reduce_minmax(const float* __restrict__ depth,
                                                     const float* __restrict__ obj,
                                                     float* __restrict__ ws) {
    const int b    = blockIdx.x / NBPB;
    const int part = blockIdx.x % NBPB;
    const int floats_per_part = NPIX / NBPB;         // 6272
    const int vec_per_part    = floats_per_part / 4; // 1568

    const fx4* d4 = (const fx4*)(depth + (size_t)b * NPIX + part * floats_per_part);
    const fx4* o4 = (const fx4*)(obj   + (size_t)b * NPIX + part * floats_per_part);

    float vmin = INFINITY, vmax = -INFINITY;
    for (int idx = threadIdx.x; idx < vec_per_part; idx += 256) {
        fx4 dd = d4[idx];
        fx4 oo = o4[idx];
        float p0 = dd.x * oo.x, p1 = dd.y * oo.y, p2 = dd.z * oo.z, p3 = dd.w * oo.w;
        vmin = fminf(vmin, fminf(fminf(p0, p1), fminf(p2, p3)));
        vmax = fmaxf(vmax, fmaxf(fmaxf(p0, p1), fmaxf(p2, p3)));
    }

    // wave64 shuffle reduce
    #pragma unroll
    for (int off = 32; off > 0; off >>= 1) {
        vmin = fminf(vmin, __shfl_down(vmin, off, 64));
        vmax = fmaxf(vmax, __shfl_down(vmax, off, 64));
    }
    __shared__ float smin[4], smax[4];
    const int wave = threadIdx.x >> 6;
    const int lane = threadIdx.x & 63;
    if (lane == 0) { smin[wave] = vmin; smax[wave] = vmax; }
    __syncthreads();
    if (threadIdx.x == 0) {
        float m0 = fminf(fminf(smin[0], smin[1]), fminf(smin[2], smin[3]));
        float m1 = fmaxf(fmaxf(smax[0], smax[1]), fmaxf(smax[2], smax[3]));
        ws[b * NBPB + part]             = m0;  // mins at [0, 512)
        ws[NB * NBPB + b * NBPB + part] = m1;  // maxs at [512, 1024)
    }
}

// ---------------------------------------------------------------------------
// Kernel 2: fused band + angular mask + 3-channel write.
// grid (49, 64) x 256 threads; each thread owns 4 contiguous pixels.
// fp contract OFF: replicate XLA's per-HLO-op rounding so the arccos
// ratio>1 -> NaN -> 0 boundary matches the reference.
// Output stores are nontemporal: write-once data must not evict the
// LLC-resident inputs (read again here after kernel 1 warmed them).
// ---------------------------------------------------------------------------
__global__ __launch_bounds__(256) void fused_band_mask(const float* __restrict__ depth,
                                                       const float* __restrict__ obj,
                                                       const float* __restrict__ gaze,
                                                       const int* __restrict__ head_point,
                                                       const float* __restrict__ ws,
                                                       float* __restrict__ out) {
#pragma clang fp contract(off)
    const int b = blockIdx.y;
    const int t = blockIdx.x * 256 + threadIdx.x;  // 0..12543
    const int p = t * 4;                           // pixel base; 4 stay in one row (224 % 4 == 0)
    const int i = p / HW;                          // row
    const int j = p % HW;                          // col (multiple of 4)

    // --- batch-uniform scalars (uniform addresses -> broadcast, cheap) ---
    float mn = INFINITY, mx = -INFINITY;
    #pragma unroll
    for (int k = 0; k < NBPB; ++k) {
        mn = fminf(mn, ws[b * NBPB + k]);
        mx = fmaxf(mx, ws[NB * NBPB + b * NBPB + k]);
    }
    const float fr = (mx - mn) / 24.0f;

    const int hp0 = head_point[2 * b];
    const int hp1 = head_point[2 * b + 1];
    const float gx = gaze[3 * b], gy = gaze[3 * b + 1], gz = gaze[3 * b + 2];

    const size_t ibase = (size_t)b * NPIX;
    // reference: head_depth = d[b, 0, hp0, hp1]  (row = hp0, col = hp1)
    const float head_d = depth[ibase + hp0 * HW + hp1] * obj[ibase + hp0 * HW + hp1];
    const float pd  = head_d + gz * 224.0f;
    const float nxy = sqrtf(gx * gx + gy * gy);
    const float PI32 = 3.14159274101257324f;       // float32(np.pi)

    const float t1 = 1.0f * fr, t2 = 2.0f * fr, t3 = 3.0f * fr;
    const float lo1 = pd - t1, hi1 = pd + t1;
    const float lo2 = pd - t2, hi2 = pd + t2;
    const float lo3 = pd - t3, hi3 = pd + t3;

    // --- 4 pixels ---
    fx4 dd = *(const fx4*)(depth + ibase + p);
    fx4 oo = *(const fx4*)(obj   + ibase + p);
    float dv[4] = { dd.x * oo.x, dd.y * oo.y, dd.z * oo.z, dd.w * oo.w };

    const float hp0f = (float)hp0, hp1f = (float)hp1;
    // reference mask: arr0 varies along W (cols), offset by hp0;
    //                 arr1 varies along H (rows), offset by hp1.
    const float arr1 = (float)i - hp1f;

    float x0[4], x1[4], x2[4];
    #pragma unroll
    for (int k = 0; k < 4; ++k) {
        const float arr0  = (float)(j + k) - hp0f;
        const float dot   = arr0 * gx + arr1 * gy;
        const float denom = sqrtf(arr0 * arr0 + arr1 * arr1) * nxy;
        const float ang   = acosf(dot / denom);    // ratio>1 or 0/0 -> NaN
        float mk = fmaxf(1.0f - (12.0f * ang) / PI32, 0.0f);  // fmaxf(NaN,0)=0 == nan_to_num path
        if (isnan(mk)) mk = 0.0f;                  // belt & suspenders
        const float d  = dv[k];
        const float dm = d * mk;                   // single f32 mul, same as fd_m * mask
        x0[k] = (lo1 <= d && hi1 >= d) ? dm : 0.0f;
        x1[k] = (lo2 <= d && hi2 >= d) ? dm : 0.0f;
        x2[k] = (lo3 <= d && hi3 >= d) ? dm : 0.0f;
    }

    const size_t obase = (size_t)b * 3 * NPIX + p;
    fx4 v0 = { x0[0], x0[1], x0[2], x0[3] };
    fx4 v1 = { x1[0], x1[1], x1[2], x1[3] };
    fx4 v2 = { x2[0], x2[1], x2[2], x2[3] };
    __builtin_nontemporal_store(v0, (fx4*)(out + obase));
    __builtin_nontemporal_store(v1, (fx4*)(out + obase + NPIX));
    __builtin_nontemporal_store(v2, (fx4*)(out + obase + 2 * NPIX));
}

extern "C" void kernel_launch(void* const* d_in, const int* in_sizes, int n_in,
                              void* d_out, int out_size, void* d_ws, size_t ws_size,
                              hipStream_t stream) {
    const float* depth      = (const float*)d_in[0];
    const float* obj        = (const float*)d_in[1];
    const float* gaze       = (const float*)d_in[2];
    const int*   head_point = (const int*)d_in[3];
    float* out = (float*)d_out;
    float* ws  = (float*)d_ws;   // needs 1024 floats = 4 KB

    reduce_minmax<<<NB * NBPB, 256, 0, stream>>>(depth, obj, ws);
    fused_band_mask<<<dim3(49, NB), 256, 0, stream>>>(depth, obj, gaze, head_point, ws, out);
}

// Round 5
// 93.129 us; speedup vs baseline: 1.0012x; 1.0012x over previous
//
#include <hip/hip_runtime.h>
#include <math.h>

#define HW   224
#define NPIX (HW * HW)   // 50176
#define NB   64          // batch
#define NBPB 16          // reduction partial-blocks per batch image

// native vector type — accepted by __builtin_nontemporal_store, 16-B layout
typedef float fx4 __attribute__((ext_vector_type(4)));

// ---------------------------------------------------------------------------
// Kernel 1: per-image partial min/max of d = depth * object.
// 16 partials/image -> 1024 blocks (4 blocks/CU), no atomics.
// min/max are rounding-free, so any reduction order is bit-exact vs XLA.
// ---------------------------------------------------------------------------
__global__ __launch_bounds__(256) void reduce_minmax(const float* __restrict__ depth,
                                                     const float* __restrict__ obj,
                                                     float* __restrict__ ws) {
    const int b    = blockIdx.x >> 4;
    const int part = blockIdx.x & 15;
    const int floats_per_part = NPIX / NBPB;         // 3136
    const int vec_per_part    = floats_per_part / 4; // 784

    const fx4* d4 = (const fx4*)(depth + (size_t)b * NPIX + part * floats_per_part);
    const fx4* o4 = (const fx4*)(obj   + (size_t)b * NPIX + part * floats_per_part);

    float vmin = INFINITY, vmax = -INFINITY;
    for (int idx = threadIdx.x; idx < vec_per_part; idx += 256) {
        fx4 dd = d4[idx];
        fx4 oo = o4[idx];
        float p0 = dd.x * oo.x, p1 = dd.y * oo.y, p2 = dd.z * oo.z, p3 = dd.w * oo.w;
        vmin = fminf(vmin, fminf(fminf(p0, p1), fminf(p2, p3)));
        vmax = fmaxf(vmax, fmaxf(fmaxf(p0, p1), fmaxf(p2, p3)));
    }

    #pragma unroll
    for (int off = 32; off > 0; off >>= 1) {
        vmin = fminf(vmin, __shfl_down(vmin, off, 64));
        vmax = fmaxf(vmax, __shfl_down(vmax, off, 64));
    }
    __shared__ float smin[4], smax[4];
    const int wave = threadIdx.x >> 6;
    const int lane = threadIdx.x & 63;
    if (lane == 0) { smin[wave] = vmin; smax[wave] = vmax; }
    __syncthreads();
    if (threadIdx.x == 0) {
        float m0 = fminf(fminf(smin[0], smin[1]), fminf(smin[2], smin[3]));
        float m1 = fmaxf(fmaxf(smax[0], smax[1]), fmaxf(smax[2], smax[3]));
        ws[b * NBPB + part]              = m0;  // mins at [0, 1024)
        ws[NB * NBPB + b * NBPB + part]  = m1;  // maxs at [1024, 2048)
    }
}

// ---------------------------------------------------------------------------
// Kernel 2: fused band + angular mask, 8 pixels/thread.
// Wave-uniform fast path: mask > 0 requires r = dot/denom > cos(pi/12)=0.96593.
// If no lane in the wave has r > 0.96 (conservative, NaN-safe), every output
// of this wave is exactly +0 (fd_m * 0, d >= 0) -> store zeros WITHOUT
// touching depth/obj/ws/head_point. ~92% of waves take this path.
// Taken path computes the identical contract-off f32 sequence as the
// reference (validated bit-exact in round 4).
// ---------------------------------------------------------------------------
__global__ __launch_bounds__(256) void fused_band_mask(const float* __restrict__ depth,
                                                       const float* __restrict__ obj,
                                                       const float* __restrict__ gaze,
                                                       const int* __restrict__ head_point,
                                                       const float* __restrict__ ws,
                                                       float* __restrict__ out) {
#pragma clang fp contract(off)
    const int b = blockIdx.y;
    const int t = blockIdx.x * 256 + threadIdx.x;  // 8-pixel group id
    if (t >= NPIX / 8) return;                     // 6272 groups; tail waves exit whole
    const int p = t * 8;                           // 8 pixels, same row (224 % 8 == 0)
    const int i = p / HW;                          // row
    const int j = p % HW;                          // col (multiple of 8)

    const int hp0 = head_point[2 * b];
    const int hp1 = head_point[2 * b + 1];
    const float gx = gaze[3 * b], gy = gaze[3 * b + 1];

    const float hp0f = (float)hp0, hp1f = (float)hp1;
    // reference: arr0 = cols - hp0 (W axis), arr1 = rows - hp1 (H axis)
    const float arr1 = (float)i - hp1f;
    const float nxy  = sqrtf(gx * gx + gy * gy);
    const float PI32 = 3.14159274101257324f;       // float32(np.pi)

    float r[8];
    bool anyl = false;
    #pragma unroll
    for (int k = 0; k < 8; ++k) {
        const float arr0  = (float)(j + k) - hp0f;
        const float dot   = arr0 * gx + arr1 * gy;
        const float denom = sqrtf(arr0 * arr0 + arr1 * arr1) * nxy;
        r[k] = dot / denom;                        // NaN at head point / degenerate gaze
        anyl = anyl || (r[k] > 0.96f);             // NaN -> false
    }

    const size_t obase = (size_t)b * 3 * NPIX + p;
    if (!__any(anyl)) {
        // whole wave outside the cone: all 24 outputs are exactly +0
        const fx4 z = { 0.0f, 0.0f, 0.0f, 0.0f };
        __builtin_nontemporal_store(z, (fx4*)(out + obase));
        __builtin_nontemporal_store(z, (fx4*)(out + obase + 4));
        __builtin_nontemporal_store(z, (fx4*)(out + obase + NPIX));
        __builtin_nontemporal_store(z, (fx4*)(out + obase + NPIX + 4));
        __builtin_nontemporal_store(z, (fx4*)(out + obase + 2 * NPIX));
        __builtin_nontemporal_store(z, (fx4*)(out + obase + 2 * NPIX + 4));
        return;
    }

    // --- slow path: batch-uniform scalars ---
    float mn = INFINITY, mx = -INFINITY;
    #pragma unroll
    for (int k = 0; k < NBPB; ++k) {
        mn = fminf(mn, ws[b * NBPB + k]);
        mx = fmaxf(mx, ws[NB * NBPB + b * NBPB + k]);
    }
    const float fr = (mx - mn) / 24.0f;

    const float gz = gaze[3 * b + 2];
    const size_t ibase = (size_t)b * NPIX;
    // reference: head_depth = d[b, 0, hp0, hp1]  (row = hp0, col = hp1)
    const float head_d = depth[ibase + hp0 * HW + hp1] * obj[ibase + hp0 * HW + hp1];
    const float pd = head_d + gz * 224.0f;

    const float t1 = 1.0f * fr, t2 = 2.0f * fr, t3 = 3.0f * fr;
    const float lo1 = pd - t1, hi1 = pd + t1;
    const float lo2 = pd - t2, hi2 = pd + t2;
    const float lo3 = pd - t3, hi3 = pd + t3;

    fx4 dd0 = *(const fx4*)(depth + ibase + p);
    fx4 dd1 = *(const fx4*)(depth + ibase + p + 4);
    fx4 oo0 = *(const fx4*)(obj   + ibase + p);
    fx4 oo1 = *(const fx4*)(obj   + ibase + p + 4);
    float dv[8] = { dd0.x * oo0.x, dd0.y * oo0.y, dd0.z * oo0.z, dd0.w * oo0.w,
                    dd1.x * oo1.x, dd1.y * oo1.y, dd1.z * oo1.z, dd1.w * oo1.w };

    float x0[8], x1[8], x2[8];
    #pragma unroll
    for (int k = 0; k < 8; ++k) {
        const float ang = acosf(r[k]);             // ratio>1 or 0/0 -> NaN
        float mk = fmaxf(1.0f - (12.0f * ang) / PI32, 0.0f);  // fmaxf(NaN,0)=0
        if (isnan(mk)) mk = 0.0f;
        const float d  = dv[k];
        const float dm = d * mk;                   // single f32 mul, same as fd_m * mask
        x0[k] = (lo1 <= d && hi1 >= d) ? dm : 0.0f;
        x1[k] = (lo2 <= d && hi2 >= d) ? dm : 0.0f;
        x2[k] = (lo3 <= d && hi3 >= d) ? dm : 0.0f;
    }

    fx4 v;
    v = (fx4){ x0[0], x0[1], x0[2], x0[3] }; __builtin_nontemporal_store(v, (fx4*)(out + obase));
    v = (fx4){ x0[4], x0[5], x0[6], x0[7] }; __builtin_nontemporal_store(v, (fx4*)(out + obase + 4));
    v = (fx4){ x1[0], x1[1], x1[2], x1[3] }; __builtin_nontemporal_store(v, (fx4*)(out + obase + NPIX));
    v = (fx4){ x1[4], x1[5], x1[6], x1[7] }; __builtin_nontemporal_store(v, (fx4*)(out + obase + NPIX + 4));
    v = (fx4){ x2[0], x2[1], x2[2], x2[3] }; __builtin_nontemporal_store(v, (fx4*)(out + obase + 2 * NPIX));
    v = (fx4){ x2[4], x2[5], x2[6], x2[7] }; __builtin_nontemporal_store(v, (fx4*)(out + obase + 2 * NPIX + 4));
}

extern "C" void kernel_launch(void* const* d_in, const int* in_sizes, int n_in,
                              void* d_out, int out_size, void* d_ws, size_t ws_size,
                              hipStream_t stream) {
    const float* depth      = (const float*)d_in[0];
    const float* obj        = (const float*)d_in[1];
    const float* gaze       = (const float*)d_in[2];
    const int*   head_point = (const int*)d_in[3];
    float* out = (float*)d_out;
    float* ws  = (float*)d_ws;   // needs 2048 floats = 8 KB

    reduce_minmax<<<NB * NBPB, 256, 0, stream>>>(depth, obj, ws);
    fused_band_mask<<<dim3((NPIX / 8 + 255) / 256, NB), 256, 0, stream>>>(depth, obj, gaze, head_point, ws, out);
}